// Round 4
// baseline (656.618 us; speedup 1.0000x reference)
//
#include <hip/hip_runtime.h>

#define N_TOK 4096
#define RD 64
#define CDIM 256

typedef __bf16 bf16x8 __attribute__((ext_vector_type(8)));
typedef float f32x4 __attribute__((ext_vector_type(4)));
typedef unsigned short u16;
typedef unsigned int u32;

__device__ __forceinline__ u16 f2bf(float f) {
  u32 u = __float_as_uint(f);
  u = (u + 0x7fffu + ((u >> 16) & 1u)) >> 16;  // RNE
  return (u16)u;
}

__device__ __forceinline__ u32 pack2bf(float a, float b) {
  u16 ha = __builtin_bit_cast(u16, (__bf16)a);
  u16 hb = __builtin_bit_cast(u16, (__bf16)b);
  return (u32)ha | ((u32)hb << 16);
}

__device__ __forceinline__ f32x4 zero4() {
  f32x4 z = {0.f, 0.f, 0.f, 0.f};
  return z;
}

// ---------------------------------------------------------------------------
// Projection (unchanged control): out[n][o] = sum_c W[o][c] * X[b][c][n]
// form 1 (Q/K, O=64): out stored (n, 64) bf16.  A = Xt (n-rows), B = W.
// form 2 (V,  O=256): out stored (c, n)  bf16.  A = W (o-rows), B = Xt.
// ---------------------------------------------------------------------------
__global__ __launch_bounds__(256) void proj_kernel(
    const float* __restrict__ wli, const float* __restrict__ nbi,
    const float* __restrict__ wq0, const float* __restrict__ wk0,
    const float* __restrict__ wv0, const float* __restrict__ wq1,
    const float* __restrict__ wk1, const float* __restrict__ wv1,
    u16* __restrict__ Qb, u16* __restrict__ Kb, u16* __restrict__ Vb) {
  extern __shared__ char smem[];
  const int ntile = blockIdx.x, bb = blockIdx.y, pid = blockIdx.z;
  const int tid = threadIdx.x;
  const int w = tid >> 6, lane = tid & 63, g = lane >> 4, l15 = lane & 15;
  const int n0 = ntile * 64;

  const float* X;
  const float* W;
  u16* out;
  float scale = 1.f;
  int form, nchunk;
  switch (pid) {
    case 0: X = wli; W = wq0; out = Qb + (size_t)(0 + bb) * N_TOK * RD; scale = 0.125f; form = 1; nchunk = 1; break;
    case 1: X = nbi; W = wk0; out = Kb + (size_t)(0 + bb) * N_TOK * RD; form = 1; nchunk = 1; break;
    case 2: X = nbi; W = wv0; out = Vb + (size_t)(0 + bb) * CDIM * N_TOK; form = 2; nchunk = 4; break;
    case 3: X = nbi; W = wq1; out = Qb + (size_t)(4 + bb) * N_TOK * RD; scale = 0.125f; form = 1; nchunk = 1; break;
    case 4: X = wli; W = wk1; out = Kb + (size_t)(4 + bb) * N_TOK * RD; form = 1; nchunk = 1; break;
    default: X = wli; W = wv1; out = Vb + (size_t)(4 + bb) * CDIM * N_TOK; form = 2; nchunk = 4; break;
  }
  X += (size_t)bb * CDIM * N_TOK;

#pragma unroll
  for (int rep = 0; rep < 16; ++rep) {
    int idx = rep * 256 + tid;
    int c = idx >> 4;
    int nq = (idx & 15) * 4;
    float4 v = *(const float4*)(X + (size_t)c * N_TOK + n0 + nq);
    float vv[4] = {v.x, v.y, v.z, v.w};
#pragma unroll
    for (int k = 0; k < 4; ++k) {
      int row = nq + k;
      int addr = (row * 512 + c * 2) ^ ((row & 7) << 4);
      *(u16*)(smem + addr) = f2bf(vv[k] * scale);
    }
  }

  for (int oc = 0; oc < nchunk; ++oc) {
#pragma unroll
    for (int rep = 0; rep < 16; ++rep) {
      int idx = rep * 256 + tid;
      int o = idx >> 6;
      int c4 = (idx & 63) * 4;
      float4 v = *(const float4*)(W + (size_t)(oc * 64 + o) * CDIM + c4);
      ushort4 pk = {f2bf(v.x), f2bf(v.y), f2bf(v.z), f2bf(v.w)};
      int addr = 32768 + ((o * 512 + c4 * 2) ^ ((o & 7) << 4));
      *(ushort4*)(smem + addr) = pk;
    }
    __syncthreads();

    f32x4 acc[4];
#pragma unroll
    for (int ct = 0; ct < 4; ++ct) acc[ct] = zero4();
    const int arow = w * 16 + l15;
    const int abase = (form == 1) ? 0 : 32768;
    const int bbase = (form == 1) ? 32768 : 0;
#pragma unroll
    for (int kk = 0; kk < 8; ++kk) {
      int koff = kk * 64 + g * 16;
      bf16x8 af = *(const bf16x8*)(smem + abase + ((arow * 512 + koff) ^ ((arow & 7) << 4)));
#pragma unroll
      for (int ct = 0; ct < 4; ++ct) {
        int brow = ct * 16 + l15;
        bf16x8 bfr = *(const bf16x8*)(smem + bbase + ((brow * 512 + koff) ^ ((brow & 7) << 4)));
        acc[ct] = __builtin_amdgcn_mfma_f32_16x16x32_bf16(af, bfr, acc[ct], 0, 0, 0);
      }
    }
    if (form == 1) {
#pragma unroll
      for (int ct = 0; ct < 4; ++ct)
#pragma unroll
        for (int r = 0; r < 4; ++r)
          out[(size_t)(n0 + w * 16 + g * 4 + r) * RD + ct * 16 + l15] = f2bf(acc[ct][r]);
    } else {
#pragma unroll
      for (int ct = 0; ct < 4; ++ct)
#pragma unroll
        for (int r = 0; r < 4; ++r)
          out[(size_t)(oc * 64 + w * 16 + g * 4 + r) * N_TOK + n0 + ct * 16 + l15] = f2bf(acc[ct][r]);
    }
    __syncthreads();
  }
}

// ---------------------------------------------------------------------------
// Flash attention + residual, 2-phase pipelined.
// LDS: Kbuf0 @0 (8KB) | Kbuf1 @8192 (8KB) | P @16384 (8KB, per-wave 2KB)
// K staged via global_load_lds(16B) with pre-swizzled global source:
//   linear LDS slot s=(j*8+c16) holds K[kv0+j][(c16^(j&7))*8 ..+7]
//   -> swizzled read addr (j*128+off*16)^((j&7)<<4) delivers K[j][off*8..]
// V consumed directly from global (Vt is (c,n): B-fragments are 16B rows).
// ---------------------------------------------------------------------------
__global__ __launch_bounds__(256, 2) void attn_kernel(
    const u16* __restrict__ Qb, const u16* __restrict__ Kb,
    const u16* __restrict__ Vb, const float* __restrict__ x_wli,
    const float* __restrict__ x_nbi, float* __restrict__ y) {
  extern __shared__ char smem[];
  const int ntile = blockIdx.x, bb = blockIdx.y, br = blockIdx.z;
  const int tid = threadIdx.x;
  const int w = tid >> 6, lane = tid & 63, g = lane >> 4, l15 = lane & 15;
  const int inst = br * 4 + bb;
  const u16* Q = Qb + (size_t)inst * N_TOK * RD + (size_t)ntile * 64 * RD;
  const u16* K = Kb + (size_t)inst * N_TOK * RD;
  const u16* Vt = Vb + (size_t)inst * CDIM * N_TOK;
  const float* xres = (br == 0 ? x_wli : x_nbi) + (size_t)bb * CDIM * N_TOK;
  float* yout = y + (size_t)inst * CDIM * N_TOK;

  bf16x8 qf[2];
  {
    const u16* qrow = Q + (w * 16 + l15) * RD;
    qf[0] = *(const bf16x8*)(qrow + g * 8);
    qf[1] = *(const bf16x8*)(qrow + 32 + g * 8);
  }
  f32x4 o_acc[16];
#pragma unroll
  for (int i = 0; i < 16; ++i) o_acc[i] = zero4();
  float m_ln = -1e30f, l_ln = 0.f;
  const float LOG2E = 1.44269504088896340736f;

  // --- K stage: 512 16B chunks, 2 per thread, wave-uniform LDS base ---
#define STAGE_K(kv0_, boff_)                                                     \
  {                                                                              \
    _Pragma("unroll") for (int rr = 0; rr < 2; ++rr) {                           \
      int s = w * 128 + rr * 64 + lane;                                          \
      int j = s >> 3, c16 = s & 7;                                               \
      const u16* gp = K + (size_t)((kv0_) + j) * RD + ((c16 ^ (j & 7)) * 8);     \
      char* lp = smem + (boff_) + (w * 128 + rr * 64) * 16;                      \
      __builtin_amdgcn_global_load_lds(                                          \
          (const __attribute__((address_space(1))) void*)gp,                     \
          (__attribute__((address_space(3))) void*)lp, 16, 0, 0);                \
    }                                                                            \
  }

  STAGE_K(0, 0);
  __syncthreads();

  for (int t = 0; t < 64; ++t) {
    const int kv0 = t * 64;
    const int bufOff = (t & 1) * 8192;
    if (t < 63) STAGE_K(kv0 + 64, ((t + 1) & 1) * 8192);

    // S^T = K . Q^T : D col = q-row (l15), D row = kv j
    f32x4 s[4];
#pragma unroll
    for (int jt = 0; jt < 4; ++jt) {
      f32x4 acc = zero4();
#pragma unroll
      for (int kk = 0; kk < 2; ++kk) {
        int row = jt * 16 + l15;
        int addr = bufOff + ((row * 128 + kk * 64 + g * 16) ^ ((row & 7) << 4));
        bf16x8 kf = *(const bf16x8*)(smem + addr);
        acc = __builtin_amdgcn_mfma_f32_16x16x32_bf16(kf, qf[kk], acc, 0, 0, 0);
      }
      s[jt] = acc;
    }

    // online softmax with defer-max (T13, THR=8)
    float mx = s[0][0];
#pragma unroll
    for (int jt = 0; jt < 4; ++jt)
#pragma unroll
      for (int r = 0; r < 4; ++r) mx = fmaxf(mx, s[jt][r]);
    mx = fmaxf(mx, __shfl_xor(mx, 16));
    mx = fmaxf(mx, __shfl_xor(mx, 32));
    if (!__all(mx - m_ln <= 8.f)) {
      float mnew = fmaxf(m_ln, mx);
      float corr = exp2f((m_ln - mnew) * LOG2E);
      m_ln = mnew;
      l_ln *= corr;
      float corrO[4];
#pragma unroll
      for (int r = 0; r < 4; ++r) corrO[r] = __shfl(corr, (lane & 48) | (g * 4 + r));
#pragma unroll
      for (int ct = 0; ct < 16; ++ct)
#pragma unroll
        for (int r = 0; r < 4; ++r) o_acc[ct][r] *= corrO[r];
    }
    float sum = 0.f;
#pragma unroll
    for (int jt = 0; jt < 4; ++jt)
#pragma unroll
      for (int r = 0; r < 4; ++r) {
        float p = exp2f((s[jt][r] - m_ln) * LOG2E);
        s[jt][r] = p;
        sum += p;
      }
    sum += __shfl_xor(sum, 16);
    sum += __shfl_xor(sum, 32);
    l_ln += sum;

    // write P^T pairs -> P_lds[i=l15][j], per-wave region, b32 writes
#pragma unroll
    for (int jt = 0; jt < 4; ++jt) {
      u32 lo = pack2bf(s[jt][0], s[jt][1]);
      u32 hi = pack2bf(s[jt][2], s[jt][3]);
      int base = 16384 + w * 2048 + ((l15 * 128 + jt * 32 + g * 8) ^ ((l15 & 7) << 4));
      *(u32*)(smem + base) = lo;
      *(u32*)(smem + base + 4) = hi;
    }
    __threadfence_block();  // order P writes before P fragment reads (per-wave)

    bf16x8 pf[2];
#pragma unroll
    for (int kk = 0; kk < 2; ++kk) {
      int addr = 16384 + w * 2048 + ((l15 * 128 + kk * 64 + g * 16) ^ ((l15 & 7) << 4));
      pf[kk] = *(const bf16x8*)(smem + addr);
    }

    // PV: O[i][c] += P[i][j] V[j][c];  B-fragments direct from global Vt
    __builtin_amdgcn_s_setprio(1);
#pragma unroll
    for (int ct = 0; ct < 16; ++ct) {
      const u16* vp = Vt + (size_t)(ct * 16 + l15) * N_TOK + kv0;
      bf16x8 vf0 = *(const bf16x8*)(vp + g * 8);
      bf16x8 vf1 = *(const bf16x8*)(vp + 32 + g * 8);
      o_acc[ct] = __builtin_amdgcn_mfma_f32_16x16x32_bf16(pf[0], vf0, o_acc[ct], 0, 0, 0);
      o_acc[ct] = __builtin_amdgcn_mfma_f32_16x16x32_bf16(pf[1], vf1, o_acc[ct], 0, 0, 0);
    }
    __builtin_amdgcn_s_setprio(0);
    __syncthreads();  // drains vmcnt (K prefetch) + lgkm; all waves done with bufs
  }

  // epilogue: y = x + O/l   (y layout (br,b,c,n))
  float rl = 1.f / l_ln;
  float rlO[4];
#pragma unroll
  for (int r = 0; r < 4; ++r) rlO[r] = __shfl(rl, (lane & 48) | (g * 4 + r));
  const int nbase = ntile * 64 + w * 16;
#pragma unroll
  for (int ct = 0; ct < 16; ++ct) {
    int c = ct * 16 + l15;
#pragma unroll
    for (int r = 0; r < 4; ++r) {
      size_t idx = (size_t)c * N_TOK + nbase + g * 4 + r;
      yout[idx] = xres[idx] + o_acc[ct][r] * rlO[r];
    }
  }
#undef STAGE_K
}

// ---------------------------------------------------------------------------
// BN stats: one block per (branch, channel); mean + rsqrt(var+eps) over 16384
// ---------------------------------------------------------------------------
__global__ __launch_bounds__(256) void bn_stats_kernel(const float* __restrict__ y,
                                                       float* __restrict__ stats) {
  const int idx = blockIdx.x;  // branch*256 + c
  const int br = idx >> 8, c = idx & 255;
  const float* base = y + (size_t)br * 4 * CDIM * N_TOK + (size_t)c * N_TOK;
  float s1 = 0.f, s2 = 0.f;
#pragma unroll
  for (int bb = 0; bb < 4; ++bb) {
    const float* p = base + (size_t)bb * CDIM * N_TOK;
    for (int off = threadIdx.x * 4; off < N_TOK; off += 1024) {
      float4 v = *(const float4*)(p + off);
      s1 += v.x + v.y + v.z + v.w;
      s2 += v.x * v.x + v.y * v.y + v.z * v.z + v.w * v.w;
    }
  }
#pragma unroll
  for (int msk = 1; msk < 64; msk <<= 1) {
    s1 += __shfl_xor(s1, msk);
    s2 += __shfl_xor(s2, msk);
  }
  __shared__ float a1[4], a2[4];
  const int wv = threadIdx.x >> 6, ln = threadIdx.x & 63;
  if (ln == 0) { a1[wv] = s1; a2[wv] = s2; }
  __syncthreads();
  if (threadIdx.x == 0) {
    float t1 = a1[0] + a1[1] + a1[2] + a1[3];
    float t2 = a2[0] + a2[1] + a2[2] + a2[3];
    float mean = t1 * (1.f / 16384.f);
    float var = t2 * (1.f / 16384.f) - mean * mean;
    stats[idx] = mean;
    stats[512 + idx] = rsqrtf(var + 1e-5f);
  }
}

__global__ __launch_bounds__(256) void bn_apply_kernel(
    const float* __restrict__ y, const float* __restrict__ stats,
    const float* __restrict__ g0, const float* __restrict__ b0,
    const float* __restrict__ g1, const float* __restrict__ b1,
    float* __restrict__ out) {
  size_t i4 = (size_t)blockIdx.x * 256 + threadIdx.x;  // 2M float4s
  int br = (int)(i4 >> 20);
  int c = (int)(i4 >> 10) & 255;
  float mean = stats[br * 256 + c];
  float rstd = stats[512 + br * 256 + c];
  float ga = (br ? g1 : g0)[c];
  float be = (br ? b1 : b0)[c];
  float a = rstd * ga;
  float4 v = *(const float4*)(y + i4 * 4);
  v.x = (v.x - mean) * a + be;
  v.y = (v.y - mean) * a + be;
  v.z = (v.z - mean) * a + be;
  v.w = (v.w - mean) * a + be;
  *(float4*)(out + i4 * 4) = v;
}

// ---------------------------------------------------------------------------
extern "C" void kernel_launch(void* const* d_in, const int* in_sizes, int n_in,
                              void* d_out, int out_size, void* d_ws, size_t ws_size,
                              hipStream_t stream) {
  const float* wli = (const float*)d_in[0];
  const float* nbi = (const float*)d_in[1];
  const float* wq0 = (const float*)d_in[2];
  const float* wk0 = (const float*)d_in[3];
  const float* wv0 = (const float*)d_in[4];
  const float* wq1 = (const float*)d_in[5];
  const float* wk1 = (const float*)d_in[6];
  const float* wv1 = (const float*)d_in[7];
  const float* g0 = (const float*)d_in[8];
  const float* b0 = (const float*)d_in[9];
  const float* g1 = (const float*)d_in[10];
  const float* b1 = (const float*)d_in[11];

  char* ws = (char*)d_ws;
  u16* Qb = (u16*)(ws + 0);
  u16* Kb = (u16*)(ws + 4194304);
  u16* Vb = (u16*)(ws + 8388608);
  float* y = (float*)(ws + 25165824);
  float* stats = (float*)(ws + 58720256);

  proj_kernel<<<dim3(64, 4, 6), 256, 65536, stream>>>(wli, nbi, wq0, wk0, wv0,
                                                      wq1, wk1, wv1, Qb, Kb, Vb);
  attn_kernel<<<dim3(64, 4, 2), 256, 24576, stream>>>(Qb, Kb, Vb, wli, nbi, y);
  bn_stats_kernel<<<dim3(512), 256, 0, stream>>>(y, stats);
  bn_apply_kernel<<<dim3(8192), 256, 0, stream>>>(y, stats, g0, b0, g1, b1,
                                                  (float*)d_out);
}

// Round 6
// 301.721 us; speedup vs baseline: 2.1762x; 2.1762x over previous
//
#include <hip/hip_runtime.h>

#define N_TOK 4096
#define RD 64
#define CDIM 256

typedef __bf16 bf16x8 __attribute__((ext_vector_type(8)));
typedef float f32x4 __attribute__((ext_vector_type(4)));
typedef unsigned short u16;
typedef unsigned int u32;

__device__ __forceinline__ u16 f2bf(float f) {
  u32 u = __float_as_uint(f);
  u = (u + 0x7fffu + ((u >> 16) & 1u)) >> 16;  // RNE
  return (u16)u;
}

__device__ __forceinline__ u32 pack2bf(float a, float b) {
  u16 ha = __builtin_bit_cast(u16, (__bf16)a);
  u16 hb = __builtin_bit_cast(u16, (__bf16)b);
  return (u32)ha | ((u32)hb << 16);
}

__device__ __forceinline__ f32x4 zero4() {
  f32x4 z = {0.f, 0.f, 0.f, 0.f};
  return z;
}

// ---------------------------------------------------------------------------
// Projection (unchanged): out[n][o] = sum_c W[o][c] * X[b][c][n]
// ---------------------------------------------------------------------------
__global__ __launch_bounds__(256) void proj_kernel(
    const float* __restrict__ wli, const float* __restrict__ nbi,
    const float* __restrict__ wq0, const float* __restrict__ wk0,
    const float* __restrict__ wv0, const float* __restrict__ wq1,
    const float* __restrict__ wk1, const float* __restrict__ wv1,
    u16* __restrict__ Qb, u16* __restrict__ Kb, u16* __restrict__ Vb) {
  extern __shared__ char smem[];
  const int ntile = blockIdx.x, bb = blockIdx.y, pid = blockIdx.z;
  const int tid = threadIdx.x;
  const int w = tid >> 6, lane = tid & 63, g = lane >> 4, l15 = lane & 15;
  const int n0 = ntile * 64;

  const float* X;
  const float* W;
  u16* out;
  float scale = 1.f;
  int form, nchunk;
  switch (pid) {
    case 0: X = wli; W = wq0; out = Qb + (size_t)(0 + bb) * N_TOK * RD; scale = 0.125f; form = 1; nchunk = 1; break;
    case 1: X = nbi; W = wk0; out = Kb + (size_t)(0 + bb) * N_TOK * RD; form = 1; nchunk = 1; break;
    case 2: X = nbi; W = wv0; out = Vb + (size_t)(0 + bb) * CDIM * N_TOK; form = 2; nchunk = 4; break;
    case 3: X = nbi; W = wq1; out = Qb + (size_t)(4 + bb) * N_TOK * RD; scale = 0.125f; form = 1; nchunk = 1; break;
    case 4: X = wli; W = wk1; out = Kb + (size_t)(4 + bb) * N_TOK * RD; form = 1; nchunk = 1; break;
    default: X = wli; W = wv1; out = Vb + (size_t)(4 + bb) * CDIM * N_TOK; form = 2; nchunk = 4; break;
  }
  X += (size_t)bb * CDIM * N_TOK;

#pragma unroll
  for (int rep = 0; rep < 16; ++rep) {
    int idx = rep * 256 + tid;
    int c = idx >> 4;
    int nq = (idx & 15) * 4;
    float4 v = *(const float4*)(X + (size_t)c * N_TOK + n0 + nq);
    float vv[4] = {v.x, v.y, v.z, v.w};
#pragma unroll
    for (int k = 0; k < 4; ++k) {
      int row = nq + k;
      int addr = (row * 512 + c * 2) ^ ((row & 7) << 4);
      *(u16*)(smem + addr) = f2bf(vv[k] * scale);
    }
  }

  for (int oc = 0; oc < nchunk; ++oc) {
#pragma unroll
    for (int rep = 0; rep < 16; ++rep) {
      int idx = rep * 256 + tid;
      int o = idx >> 6;
      int c4 = (idx & 63) * 4;
      float4 v = *(const float4*)(W + (size_t)(oc * 64 + o) * CDIM + c4);
      ushort4 pk = {f2bf(v.x), f2bf(v.y), f2bf(v.z), f2bf(v.w)};
      int addr = 32768 + ((o * 512 + c4 * 2) ^ ((o & 7) << 4));
      *(ushort4*)(smem + addr) = pk;
    }
    __syncthreads();

    f32x4 acc[4];
#pragma unroll
    for (int ct = 0; ct < 4; ++ct) acc[ct] = zero4();
    const int arow = w * 16 + l15;
    const int abase = (form == 1) ? 0 : 32768;
    const int bbase = (form == 1) ? 32768 : 0;
#pragma unroll
    for (int kk = 0; kk < 8; ++kk) {
      int koff = kk * 64 + g * 16;
      bf16x8 af = *(const bf16x8*)(smem + abase + ((arow * 512 + koff) ^ ((arow & 7) << 4)));
#pragma unroll
      for (int ct = 0; ct < 4; ++ct) {
        int brow = ct * 16 + l15;
        bf16x8 bfr = *(const bf16x8*)(smem + bbase + ((brow * 512 + koff) ^ ((brow & 7) << 4)));
        acc[ct] = __builtin_amdgcn_mfma_f32_16x16x32_bf16(af, bfr, acc[ct], 0, 0, 0);
      }
    }
    if (form == 1) {
#pragma unroll
      for (int ct = 0; ct < 4; ++ct)
#pragma unroll
        for (int r = 0; r < 4; ++r)
          out[(size_t)(n0 + w * 16 + g * 4 + r) * RD + ct * 16 + l15] = f2bf(acc[ct][r]);
    } else {
#pragma unroll
      for (int ct = 0; ct < 4; ++ct)
#pragma unroll
        for (int r = 0; r < 4; ++r)
          out[(size_t)(oc * 64 + w * 16 + g * 4 + r) * N_TOK + n0 + ct * 16 + l15] = f2bf(acc[ct][r]);
    }
    __syncthreads();
  }
}

// ---------------------------------------------------------------------------
// Flash attention + residual, 2-phase pipeline, 1 barrier/tile.
// LDS (80KB): buf[2] x { K 8KB | V 32KB } @ t*40960.
// K,V staged via global_load_lds(16B), pre-swizzled global source:
//   linear slot s=(row*8+c16) holds row bytes of 16B-chunk (c16 ^ (row&7))
//   -> read addr (row*128 + cs*16)^((row&7)<<4) delivers chunk cs of row.
// P in registers: pack bf16 pairs; exchange with COMPILE-TIME pk indices
// (shfl evaluates operand in the SOURCE lane -> runtime index was the r5 bug):
// shuffle both jt candidates, select by destination's g>>1.
// grid 1-D 512; inst = wgid&7 clusters each instance on one XCD (L2 local).
// ---------------------------------------------------------------------------
__global__ __launch_bounds__(256, 2) void attn_kernel(
    const u16* __restrict__ Qb, const u16* __restrict__ Kb,
    const u16* __restrict__ Vb, const float* __restrict__ x_wli,
    const float* __restrict__ x_nbi, float* __restrict__ y) {
  extern __shared__ char smem[];
  const int wgid = blockIdx.x;
  const int inst = wgid & 7;         // XCD-clustered instance
  const int ntile = wgid >> 3;
  const int br = inst >> 2, bb = inst & 3;
  const int tid = threadIdx.x;
  const int w = tid >> 6, lane = tid & 63, g = lane >> 4, l15 = lane & 15;
  const u16* Q = Qb + (size_t)inst * N_TOK * RD + (size_t)ntile * 64 * RD;
  const u16* K = Kb + (size_t)inst * N_TOK * RD;
  const u16* Vt = Vb + (size_t)inst * CDIM * N_TOK;
  const float* xres = (br == 0 ? x_wli : x_nbi) + (size_t)bb * CDIM * N_TOK;
  float* yout = y + (size_t)inst * CDIM * N_TOK;

  bf16x8 qf[2];
  {
    const u16* qrow = Q + (w * 16 + l15) * RD;
    qf[0] = *(const bf16x8*)(qrow + g * 8);
    qf[1] = *(const bf16x8*)(qrow + 32 + g * 8);
  }
  f32x4 o_acc[16];
#pragma unroll
  for (int i = 0; i < 16; ++i) o_acc[i] = zero4();
  float m_ln = -1e30f, l_ln = 0.f;
  const float LOG2E = 1.44269504088896340736f;

  // stage K (512 chunks) + V (2048 chunks); dest wave-uniform base (+lane*16 by HW)
#define STAGE_KV(kv0_, boff_)                                                    \
  {                                                                              \
    _Pragma("unroll") for (int rr = 0; rr < 2; ++rr) {                           \
      int s = w * 128 + rr * 64 + lane;                                          \
      int j = s >> 3, c16 = s & 7;                                               \
      const u16* gp = K + (size_t)((kv0_) + j) * RD + ((c16 ^ (j & 7)) * 8);     \
      char* lp = smem + (boff_) + (w * 128 + rr * 64) * 16;                      \
      __builtin_amdgcn_global_load_lds(                                          \
          (const __attribute__((address_space(1))) void*)gp,                     \
          (__attribute__((address_space(3))) void*)lp, 16, 0, 0);                \
    }                                                                            \
    _Pragma("unroll") for (int rr = 0; rr < 8; ++rr) {                           \
      int s = w * 512 + rr * 64 + lane;                                          \
      int c = s >> 3, c16 = s & 7;                                               \
      const u16* gp = Vt + (size_t)c * N_TOK + (kv0_) + ((c16 ^ (c & 7)) * 8);   \
      char* lp = smem + (boff_) + 8192 + (w * 512 + rr * 64) * 16;               \
      __builtin_amdgcn_global_load_lds(                                          \
          (const __attribute__((address_space(1))) void*)gp,                     \
          (__attribute__((address_space(3))) void*)lp, 16, 0, 0);                \
    }                                                                            \
  }

  STAGE_KV(0, 0);
  __syncthreads();

  for (int t = 0; t < 64; ++t) {
    const int kv0 = t * 64;
    const int bufOff = (t & 1) * 40960;
    if (t < 63) STAGE_KV(kv0 + 64, ((t + 1) & 1) * 40960);

    // S^T = K . Q^T : D col = q-row (l15), D row = kv j
    f32x4 s[4];
#pragma unroll
    for (int jt = 0; jt < 4; ++jt) {
      f32x4 acc = zero4();
#pragma unroll
      for (int kk = 0; kk < 2; ++kk) {
        int row = jt * 16 + l15;
        int addr = bufOff + ((row * 128 + kk * 64 + g * 16) ^ ((row & 7) << 4));
        bf16x8 kf = *(const bf16x8*)(smem + addr);
        acc = __builtin_amdgcn_mfma_f32_16x16x32_bf16(kf, qf[kk], acc, 0, 0, 0);
      }
      s[jt] = acc;
    }

    // online softmax with defer-max (THR=8)
    float mx = s[0][0];
#pragma unroll
    for (int jt = 0; jt < 4; ++jt)
#pragma unroll
      for (int r = 0; r < 4; ++r) mx = fmaxf(mx, s[jt][r]);
    mx = fmaxf(mx, __shfl_xor(mx, 16));
    mx = fmaxf(mx, __shfl_xor(mx, 32));
    if (!__all(mx - m_ln <= 8.f)) {
      float mnew = fmaxf(m_ln, mx);
      float corr = exp2f((m_ln - mnew) * LOG2E);
      m_ln = mnew;
      l_ln *= corr;
      float corrO[4];
#pragma unroll
      for (int r = 0; r < 4; ++r) corrO[r] = __shfl(corr, (lane & 48) | (g * 4 + r));
#pragma unroll
      for (int ct = 0; ct < 16; ++ct)
#pragma unroll
        for (int r = 0; r < 4; ++r) o_acc[ct][r] *= corrO[r];
    }
    float sum = 0.f;
#pragma unroll
    for (int jt = 0; jt < 4; ++jt)
#pragma unroll
      for (int r = 0; r < 4; ++r) {
        float p = exp2f((s[jt][r] - m_ln) * LOG2E);
        s[jt][r] = p;
        sum += p;
      }
    sum += __shfl_xor(sum, 16);
    sum += __shfl_xor(sum, 32);
    l_ln += sum;

    // P exchange, all pk indices COMPILE-TIME (shfl operand evaluated at src):
    // lane(g,l15) owns P[q=l15][j=jt*16+g*4+r] as pk[jt*2+(r>>1)].
    // pf[kk] word m needs j={32kk+8g+2m, +1}: src lane (2(g&1)+(m>>1))*16+l15,
    // pk[(2kk + (g>>1))*2 + (m&1)] -> shuffle both jt variants, select by g>>1.
    u32 pk[8];
#pragma unroll
    for (int jt = 0; jt < 4; ++jt) {
      pk[jt * 2] = pack2bf(s[jt][0], s[jt][1]);
      pk[jt * 2 + 1] = pack2bf(s[jt][2], s[jt][3]);
    }
    bf16x8 pf[2];
#pragma unroll
    for (int kk = 0; kk < 2; ++kk) {
      u32 wsel[4];
#pragma unroll
      for (int m = 0; m < 4; ++m) {
        int src = (2 * (g & 1) + (m >> 1)) * 16 + l15;
        u32 w0 = (u32)__shfl((int)pk[(2 * kk + 0) * 2 + (m & 1)], src);
        u32 w1 = (u32)__shfl((int)pk[(2 * kk + 1) * 2 + (m & 1)], src);
        wsel[m] = (g & 2) ? w1 : w0;
      }
      int4 pw = {(int)wsel[0], (int)wsel[1], (int)wsel[2], (int)wsel[3]};
      pf[kk] = __builtin_bit_cast(bf16x8, pw);
    }

    // PV: O[q][c] += P[q][j] V[j][c];  V from LDS (staged once, shared by waves)
    __builtin_amdgcn_s_setprio(1);
#pragma unroll
    for (int ct = 0; ct < 16; ++ct) {
      int c = ct * 16 + l15;
      int vb = bufOff + 8192;
      bf16x8 vf0 = *(const bf16x8*)(smem + vb + ((c * 128 + g * 16) ^ ((c & 7) << 4)));
      bf16x8 vf1 = *(const bf16x8*)(smem + vb + ((c * 128 + 64 + g * 16) ^ ((c & 7) << 4)));
      o_acc[ct] = __builtin_amdgcn_mfma_f32_16x16x32_bf16(pf[0], vf0, o_acc[ct], 0, 0, 0);
      o_acc[ct] = __builtin_amdgcn_mfma_f32_16x16x32_bf16(pf[1], vf1, o_acc[ct], 0, 0, 0);
    }
    __builtin_amdgcn_s_setprio(0);
    __syncthreads();  // single barrier: drains prefetch vmcnt; bufs swap safely
  }

  // epilogue: y = x + O/l   (y layout (br,b,c,n))
  float rl = 1.f / l_ln;
  float rlO[4];
#pragma unroll
  for (int r = 0; r < 4; ++r) rlO[r] = __shfl(rl, (lane & 48) | (g * 4 + r));
  const int nbase = ntile * 64 + w * 16;
#pragma unroll
  for (int ct = 0; ct < 16; ++ct) {
    int c = ct * 16 + l15;
#pragma unroll
    for (int r = 0; r < 4; ++r) {
      size_t idx = (size_t)c * N_TOK + nbase + g * 4 + r;
      yout[idx] = xres[idx] + o_acc[ct][r] * rlO[r];
    }
  }
#undef STAGE_KV
}

// ---------------------------------------------------------------------------
// BN stats: one block per (branch, channel); mean + rsqrt(var+eps) over 16384
// ---------------------------------------------------------------------------
__global__ __launch_bounds__(256) void bn_stats_kernel(const float* __restrict__ y,
                                                       float* __restrict__ stats) {
  const int idx = blockIdx.x;  // branch*256 + c
  const int br = idx >> 8, c = idx & 255;
  const float* base = y + (size_t)br * 4 * CDIM * N_TOK + (size_t)c * N_TOK;
  float s1 = 0.f, s2 = 0.f;
#pragma unroll
  for (int bb = 0; bb < 4; ++bb) {
    const float* p = base + (size_t)bb * CDIM * N_TOK;
    for (int off = threadIdx.x * 4; off < N_TOK; off += 1024) {
      float4 v = *(const float4*)(p + off);
      s1 += v.x + v.y + v.z + v.w;
      s2 += v.x * v.x + v.y * v.y + v.z * v.z + v.w * v.w;
    }
  }
#pragma unroll
  for (int msk = 1; msk < 64; msk <<= 1) {
    s1 += __shfl_xor(s1, msk);
    s2 += __shfl_xor(s2, msk);
  }
  __shared__ float a1[4], a2[4];
  const int wv = threadIdx.x >> 6, ln = threadIdx.x & 63;
  if (ln == 0) { a1[wv] = s1; a2[wv] = s2; }
  __syncthreads();
  if (threadIdx.x == 0) {
    float t1 = a1[0] + a1[1] + a1[2] + a1[3];
    float t2 = a2[0] + a2[1] + a2[2] + a2[3];
    float mean = t1 * (1.f / 16384.f);
    float var = t2 * (1.f / 16384.f) - mean * mean;
    stats[idx] = mean;
    stats[512 + idx] = rsqrtf(var + 1e-5f);
  }
}

__global__ __launch_bounds__(256) void bn_apply_kernel(
    const float* __restrict__ y, const float* __restrict__ stats,
    const float* __restrict__ g0, const float* __restrict__ b0,
    const float* __restrict__ g1, const float* __restrict__ b1,
    float* __restrict__ out) {
  size_t i4 = (size_t)blockIdx.x * 256 + threadIdx.x;  // 2M float4s
  int br = (int)(i4 >> 20);
  int c = (int)(i4 >> 10) & 255;
  float mean = stats[br * 256 + c];
  float rstd = stats[512 + br * 256 + c];
  float ga = (br ? g1 : g0)[c];
  float be = (br ? b1 : b0)[c];
  float a = rstd * ga;
  float4 v = *(const float4*)(y + i4 * 4);
  v.x = (v.x - mean) * a + be;
  v.y = (v.y - mean) * a + be;
  v.z = (v.z - mean) * a + be;
  v.w = (v.w - mean) * a + be;
  *(float4*)(out + i4 * 4) = v;
}

// ---------------------------------------------------------------------------
extern "C" void kernel_launch(void* const* d_in, const int* in_sizes, int n_in,
                              void* d_out, int out_size, void* d_ws, size_t ws_size,
                              hipStream_t stream) {
  const float* wli = (const float*)d_in[0];
  const float* nbi = (const float*)d_in[1];
  const float* wq0 = (const float*)d_in[2];
  const float* wk0 = (const float*)d_in[3];
  const float* wv0 = (const float*)d_in[4];
  const float* wq1 = (const float*)d_in[5];
  const float* wk1 = (const float*)d_in[6];
  const float* wv1 = (const float*)d_in[7];
  const float* g0 = (const float*)d_in[8];
  const float* b0 = (const float*)d_in[9];
  const float* g1 = (const float*)d_in[10];
  const float* b1 = (const float*)d_in[11];

  char* ws = (char*)d_ws;
  u16* Qb = (u16*)(ws + 0);
  u16* Kb = (u16*)(ws + 4194304);
  u16* Vb = (u16*)(ws + 8388608);
  float* y = (float*)(ws + 25165824);
  float* stats = (float*)(ws + 58720256);

  proj_kernel<<<dim3(64, 4, 6), 256, 65536, stream>>>(wli, nbi, wq0, wk0, wv0,
                                                      wq1, wk1, wv1, Qb, Kb, Vb);
  attn_kernel<<<dim3(512), 256, 81920, stream>>>(Qb, Kb, Vb, wli, nbi, y);
  bn_stats_kernel<<<dim3(512), 256, 0, stream>>>(y, stats);
  bn_apply_kernel<<<dim3(8192), 256, 0, stream>>>(y, stats, g0, b0, g1, b1,
                                                  (float*)d_out);
}